// Round 1
// baseline (156.171 us; speedup 1.0000x reference)
//
#include <hip/hip_runtime.h>
#include <math.h>

#define BB 4
#define SS 512
#define HH 256
#define NRELS 99
#define QR_STRIDE 100

// ws layout (float offsets). Total 1384448 floats = ~5.3 MB.
#define WQT_OFF 0
#define WKT_OFF 65536
#define Q_OFF   131072
#define K_OFF   655360
#define QR_OFF  1179648

static __device__ __forceinline__ void fma4(float4& a, const float4& w, float x) {
    a.x = fmaf(x, w.x, a.x);
    a.y = fmaf(x, w.y, a.y);
    a.z = fmaf(x, w.z, a.z);
    a.w = fmaf(x, w.w, a.w);
}

// K0: transpose Wq, Wk -> ws (WT[a][b] = W[b][a]) so K1's inner loop reads
// WT rows coalesced. grid (8,8,2) x 256 threads, 32x32 tiles, +1 pad.
__global__ __launch_bounds__(256) void transpose_w(const float* __restrict__ Wq,
                                                   const float* __restrict__ Wk,
                                                   float* __restrict__ ws) {
    __shared__ float tile[32][33];
    const float* W = (blockIdx.z == 0) ? Wq : Wk;
    float* WT = ws + ((blockIdx.z == 0) ? WQT_OFF : WKT_OFF);
    int tx = blockIdx.x * 32;
    int ty = blockIdx.y * 32;
    int c = threadIdx.x & 31;
    int r0 = threadIdx.x >> 5;  // 0..7
#pragma unroll
    for (int rr = 0; rr < 4; rr++) {
        int r = r0 + 8 * rr;
        tile[r][c] = W[(ty + r) * HH + (tx + c)];
    }
    __syncthreads();
#pragma unroll
    for (int rr = 0; rr < 4; rr++) {
        int r = r0 + 8 * rr;
        WT[(tx + r) * HH + (ty + c)] = tile[c][r];  // = W[ty+c][tx+r]
    }
}

// K1: projections. rows 0..2047 -> q = queries@WqT + bq ; rows 2048..4095 -> k.
// 16 rows/block, 256 blocks, 256 threads. Thread: rg=tid/64 rows {rg,rg+4,rg+8,rg+12},
// c=tid%64 cols {4c..4c+3}. Per 4-h' step: 4 global b128 (WT, coalesced 1KB/instr) +
// 4 LDS b128 (x rows, broadcast) vs 64 FMA.
__global__ __launch_bounds__(256) void proj_kernel(const float* __restrict__ queries,
                                                   const float* __restrict__ keys,
                                                   const float* __restrict__ bq,
                                                   const float* __restrict__ bk,
                                                   float* __restrict__ ws) {
    __shared__ float x_l[16][256];
    int row0 = blockIdx.x * 16;
    bool is_q = (row0 < BB * SS);
    const float* x = is_q ? (queries + row0 * HH) : (keys + (row0 - BB * SS) * HH);
    const float4* wt4 = (const float4*)(ws + (is_q ? WQT_OFF : WKT_OFF));
    const float4* b4 = (const float4*)(is_q ? bq : bk);
    float4* out4 = (float4*)(ws + (is_q ? Q_OFF + row0 * HH : K_OFF + (row0 - BB * SS) * HH));

    const float4* x4 = (const float4*)x;
    float4* xl4 = (float4*)&x_l[0][0];
#pragma unroll
    for (int it = 0; it < 4; it++) {
        int idx = it * 256 + threadIdx.x;  // 1024 float4
        xl4[idx] = x4[idx];
    }
    __syncthreads();

    int c = threadIdx.x & 63;
    int rg = threadIdx.x >> 6;  // 0..3
    float4 acc[4];
#pragma unroll
    for (int r = 0; r < 4; r++) acc[r] = make_float4(0.f, 0.f, 0.f, 0.f);

    for (int hp = 0; hp < HH; hp += 4) {
        float4 w0 = wt4[(hp + 0) * 64 + c];
        float4 w1 = wt4[(hp + 1) * 64 + c];
        float4 w2 = wt4[(hp + 2) * 64 + c];
        float4 w3 = wt4[(hp + 3) * 64 + c];
#pragma unroll
        for (int r = 0; r < 4; r++) {
            float4 xv = *(const float4*)&x_l[rg + 4 * r][hp];
            fma4(acc[r], w0, xv.x);
            fma4(acc[r], w1, xv.y);
            fma4(acc[r], w2, xv.z);
            fma4(acc[r], w3, xv.w);
        }
    }
    float4 bias = b4[c];
#pragma unroll
    for (int r = 0; r < 4; r++) {
        float4 o = acc[r];
        o.x += bias.x; o.y += bias.y; o.z += bias.z; o.w += bias.w;
        out4[(rg + 4 * r) * 64 + c] = o;
    }
}

// K2: qr_table[row][r] = q[row] . rel_emb[r].  8 rows/block, 256 blocks, 128 thr.
// Thread r (<99) streams rel_emb[r] (L2-resident, 101KB) against 8 LDS q rows.
__global__ __launch_bounds__(128) void qr_kernel(const float* __restrict__ rel_emb,
                                                 float* __restrict__ ws) {
    __shared__ float q_l[8][256];
    int r0 = blockIdx.x * 8;
    const float4* q4 = (const float4*)(ws + Q_OFF + r0 * HH);
    float4* ql4 = (float4*)&q_l[0][0];
#pragma unroll
    for (int it = 0; it < 4; it++) {
        int idx = it * 128 + threadIdx.x;  // 512 float4
        ql4[idx] = q4[idx];
    }
    __syncthreads();
    int r = threadIdx.x;
    if (r < NRELS) {
        const float4* e4 = (const float4*)(rel_emb + r * HH);
        float acc[8];
#pragma unroll
        for (int rr = 0; rr < 8; rr++) acc[rr] = 0.f;
        for (int h4 = 0; h4 < 64; h4++) {
            float4 e = e4[h4];
#pragma unroll
            for (int rr = 0; rr < 8; rr++) {
                float4 qv = *(const float4*)&q_l[rr][h4 * 4];
                acc[rr] = fmaf(qv.x, e.x, acc[rr]);
                acc[rr] = fmaf(qv.y, e.y, acc[rr]);
                acc[rr] = fmaf(qv.z, e.z, acc[rr]);
                acc[rr] = fmaf(qv.w, e.w, acc[rr]);
            }
        }
#pragma unroll
        for (int rr = 0; rr < 8; rr++)
            ws[QR_OFF + (r0 + rr) * QR_STRIDE + r] = acc[rr];
    }
}

// K3: fused qk + qr-gather + scale + softmax. Block = (batch b, 8-row i-tile),
// 256 blocks x 256 threads. k[b] staged per 16-h tile transposed: kt[h][j]
// (LDS write bank = j%32 = lane -> conflict-free; compute reads b128 over j,
// contiguous across lanes -> conflict-free). Thread: jl=tid%32, ig=(tid/32)%3..,
// jh=tid/128; rows {ig, ig+4}, cols {4jl..+3} + 128*{2jh, 2jh+1}. acc 2x2 float4.
__global__ __launch_bounds__(256) void attn_kernel(const int* __restrict__ relations,
                                                   float* __restrict__ ws,
                                                   float* __restrict__ out) {
    __shared__ float kt[16][512];
    __shared__ float q_l[8][256];
    __shared__ float qr_l[8 * QR_STRIDE];
    __shared__ float red_m[8][2];
    __shared__ float red_s[8][2];

    int bx = blockIdx.x;
    int b = bx >> 6;
    int i0 = (bx & 63) * 8;

    // load q rows and qr rows
    const float4* q4 = (const float4*)(ws + Q_OFF + (b * SS + i0) * HH);
    float4* ql4 = (float4*)&q_l[0][0];
#pragma unroll
    for (int it = 0; it < 2; it++)
        ql4[it * 256 + threadIdx.x] = q4[it * 256 + threadIdx.x];
    const float4* qr4 = (const float4*)(ws + QR_OFF + (b * SS + i0) * QR_STRIDE);
    float4* qrl4 = (float4*)qr_l;
    if (threadIdx.x < 200) qrl4[threadIdx.x] = qr4[threadIdx.x];

    int jl = threadIdx.x & 31;
    int ig = (threadIdx.x >> 5) & 3;
    int jh = threadIdx.x >> 7;  // 0/1
    int jc0 = 4 * jl + 128 * (2 * jh);
    int jc1 = 4 * jl + 128 * (2 * jh + 1);

    float4 acc[2][2];
#pragma unroll
    for (int r = 0; r < 2; r++)
#pragma unroll
        for (int g = 0; g < 2; g++) acc[r][g] = make_float4(0.f, 0.f, 0.f, 0.f);

    const float4* kg4 = (const float4*)(ws + K_OFF + b * SS * HH);
    int s_jl = threadIdx.x & 31;
    int s_hq = (threadIdx.x >> 5) & 3;
    int s_jh = threadIdx.x >> 7;

    for (int h0 = 0; h0 < HH; h0 += 16) {
        __syncthreads();  // protect kt from previous tile's readers (also covers initial loads)
#pragma unroll
        for (int iter = 0; iter < 8; iter++) {
            int j = s_jl + 32 * (s_jh + 2 * iter);
            float4 kv = kg4[j * 64 + (h0 >> 2) + s_hq];
            kt[4 * s_hq + 0][j] = kv.x;
            kt[4 * s_hq + 1][j] = kv.y;
            kt[4 * s_hq + 2][j] = kv.z;
            kt[4 * s_hq + 3][j] = kv.w;
        }
        __syncthreads();
#pragma unroll
        for (int hh4 = 0; hh4 < 4; hh4++) {
            float4 qa = *(const float4*)&q_l[ig][h0 + 4 * hh4];
            float4 qb = *(const float4*)&q_l[ig + 4][h0 + 4 * hh4];
            const float* qap = (const float*)&qa;
            const float* qbp = (const float*)&qb;
#pragma unroll
            for (int t = 0; t < 4; t++) {
                const float* krow = &kt[4 * hh4 + t][0];
                float4 k0 = *(const float4*)(krow + jc0);
                float4 k1 = *(const float4*)(krow + jc1);
                fma4(acc[0][0], k0, qap[t]);
                fma4(acc[0][1], k1, qap[t]);
                fma4(acc[1][0], k0, qbp[t]);
                fma4(acc[1][1], k1, qbp[t]);
            }
        }
    }

    // epilogue: logits = (qk + qr_gather) * scale; row softmax over 512 j
    const float scale = 0.0625f;  // 1/sqrt(256)
    const int* relb = relations + (b * SS + i0) * SS;
    float lg[2][2][4];
#pragma unroll
    for (int r = 0; r < 2; r++) {
        int i_loc = ig + 4 * r;
#pragma unroll
        for (int gg = 0; gg < 2; gg++) {
            int g = 2 * jh + gg;
            int4 rv = *(const int4*)(relb + i_loc * SS + 4 * jl + 128 * g);
            const int* rp = (const int*)&rv;
            const float* ap = (const float*)&acc[r][gg];
#pragma unroll
            for (int t = 0; t < 4; t++)
                lg[r][gg][t] = (ap[t] + qr_l[i_loc * QR_STRIDE + rp[t]]) * scale;
        }
    }

    // row max: per-thread 8 values -> shfl over 32 lanes -> combine 2 halves via LDS
    float ml[2];
#pragma unroll
    for (int r = 0; r < 2; r++) {
        float m = -1e30f;
#pragma unroll
        for (int gg = 0; gg < 2; gg++)
#pragma unroll
            for (int t = 0; t < 4; t++) m = fmaxf(m, lg[r][gg][t]);
#pragma unroll
        for (int d = 16; d >= 1; d >>= 1) m = fmaxf(m, __shfl_xor(m, d, 32));
        ml[r] = m;
    }
    if (jl == 0) {
        red_m[ig][jh] = ml[0];
        red_m[ig + 4][jh] = ml[1];
    }
    __syncthreads();
    float M[2];
    M[0] = fmaxf(red_m[ig][0], red_m[ig][1]);
    M[1] = fmaxf(red_m[ig + 4][0], red_m[ig + 4][1]);

    float sl[2] = {0.f, 0.f};
#pragma unroll
    for (int r = 0; r < 2; r++) {
#pragma unroll
        for (int gg = 0; gg < 2; gg++)
#pragma unroll
            for (int t = 0; t < 4; t++) {
                float e = __expf(lg[r][gg][t] - M[r]);
                lg[r][gg][t] = e;
                sl[r] += e;
            }
#pragma unroll
        for (int d = 16; d >= 1; d >>= 1) sl[r] += __shfl_xor(sl[r], d, 32);
    }
    if (jl == 0) {
        red_s[ig][jh] = sl[0];
        red_s[ig + 4][jh] = sl[1];
    }
    __syncthreads();
    float inv[2];
    inv[0] = 1.f / (red_s[ig][0] + red_s[ig][1]);
    inv[1] = 1.f / (red_s[ig + 4][0] + red_s[ig + 4][1]);

    float4* outb = (float4*)(out + (b * SS + i0) * SS);
#pragma unroll
    for (int r = 0; r < 2; r++) {
        int i_loc = ig + 4 * r;
#pragma unroll
        for (int gg = 0; gg < 2; gg++) {
            int g = 2 * jh + gg;
            float4 ov;
            ov.x = lg[r][gg][0] * inv[r];
            ov.y = lg[r][gg][1] * inv[r];
            ov.z = lg[r][gg][2] * inv[r];
            ov.w = lg[r][gg][3] * inv[r];
            outb[i_loc * 128 + jl + 32 * g] = ov;
        }
    }
}

extern "C" void kernel_launch(void* const* d_in, const int* in_sizes, int n_in,
                              void* d_out, int out_size, void* d_ws, size_t ws_size,
                              hipStream_t stream) {
    const float* queries = (const float*)d_in[0];
    const float* keys = (const float*)d_in[1];
    const int* relations = (const int*)d_in[2];
    const float* Wq = (const float*)d_in[3];
    const float* bq = (const float*)d_in[4];
    const float* Wk = (const float*)d_in[5];
    const float* bk = (const float*)d_in[6];
    const float* rel_emb = (const float*)d_in[7];
    float* ws = (float*)d_ws;
    float* out = (float*)d_out;

    hipLaunchKernelGGL(transpose_w, dim3(8, 8, 2), dim3(256), 0, stream, Wq, Wk, ws);
    hipLaunchKernelGGL(proj_kernel, dim3(256), dim3(256), 0, stream, queries, keys, bq, bk, ws);
    hipLaunchKernelGGL(qr_kernel, dim3(256), dim3(128), 0, stream, rel_emb, ws);
    hipLaunchKernelGGL(attn_kernel, dim3(256), dim3(256), 0, stream, relations, ws, out);
}

// Round 3
// 141.328 us; speedup vs baseline: 1.1050x; 1.1050x over previous
//
#include <hip/hip_runtime.h>
#include <math.h>

#define BB 4
#define SS 512
#define HH 256
#define BS 2048      // B*S
#define NRELS 99

// ws layout (float offsets)
#define WQT_OFF 0          // Wq^T [256][256]
#define WKT_OFF 65536      // Wk^T [256][256]
#define RET_OFF 131072     // rel_emb^T [256][128]  (r padded 99->128, zeros)
#define Q_OFF   163840     // q row-major [2048][256]
#define KT_OFF  688128     // k^T [256][2048]  (col = b*512 + j)

static __device__ __forceinline__ void fma4(float4& a, const float4& w, float x) {
    a.x = fmaf(x, w.x, a.x);
    a.y = fmaf(x, w.y, a.y);
    a.z = fmaf(x, w.z, a.z);
    a.w = fmaf(x, w.w, a.w);
}

// K0: z=0: Wq->WqT, z=1: Wk->WkT, z=2 (y<4): rel_emb[99][256] -> re_t[256][128] (zero pad).
__global__ __launch_bounds__(256) void prep_kernel(const float* __restrict__ Wq,
                                                   const float* __restrict__ Wk,
                                                   const float* __restrict__ rel_emb,
                                                   float* __restrict__ ws) {
    __shared__ float tile[32][33];
    int c = threadIdx.x & 31;
    int r0 = threadIdx.x >> 5;  // 0..7
    if (blockIdx.z < 2) {
        const float* W = (blockIdx.z == 0) ? Wq : Wk;
        float* WT = ws + ((blockIdx.z == 0) ? WQT_OFF : WKT_OFF);
        int tx = blockIdx.x * 32;
        int ty = blockIdx.y * 32;
#pragma unroll
        for (int rr = 0; rr < 4; rr++) {
            int r = r0 + 8 * rr;
            tile[r][c] = W[(ty + r) * HH + (tx + c)];
        }
        __syncthreads();
#pragma unroll
        for (int rr = 0; rr < 4; rr++) {
            int r = r0 + 8 * rr;
            WT[(tx + r) * HH + (ty + c)] = tile[c][r];
        }
    } else {
        if (blockIdx.y >= 4) return;
        int tx = blockIdx.x * 32;  // h base (0..224)
        int ty = blockIdx.y * 32;  // rel base (0..96)
#pragma unroll
        for (int rr = 0; rr < 4; rr++) {
            int r = r0 + 8 * rr;
            tile[r][c] = (ty + r < NRELS) ? rel_emb[(ty + r) * HH + (tx + c)] : 0.f;
        }
        __syncthreads();
#pragma unroll
        for (int rr = 0; rr < 4; rr++) {
            int r = r0 + 8 * rr;
            ws[RET_OFF + (tx + r) * 128 + (ty + c)] = tile[c][r];  // re_t[h][rel]
        }
    }
}

// K1: projections. Blocks 0..127: q rows (row-major out). Blocks 128..255: k rows,
// written TRANSPOSED to KT (via LDS stage) so attn staging is coalesced.
__global__ __launch_bounds__(256) void proj_kernel(const float* __restrict__ queries,
                                                   const float* __restrict__ keys,
                                                   const float* __restrict__ bq,
                                                   const float* __restrict__ bk,
                                                   float* __restrict__ ws) {
    __shared__ float x_l[16][256];
    __shared__ float st[16][260];  // k-transpose stage (260*4=1040B=65*16 -> float4 aligned rows)
    int row0 = blockIdx.x * 16;
    bool is_q = (row0 < BS);
    const float* x = is_q ? (queries + row0 * HH) : (keys + (row0 - BS) * HH);
    const float4* wt4 = (const float4*)(ws + (is_q ? WQT_OFF : WKT_OFF));
    const float4* b4 = (const float4*)(is_q ? bq : bk);

    const float4* x4 = (const float4*)x;
    float4* xl4 = (float4*)&x_l[0][0];
#pragma unroll
    for (int it = 0; it < 4; it++) {
        int idx = it * 256 + threadIdx.x;
        xl4[idx] = x4[idx];
    }
    __syncthreads();

    int c = threadIdx.x & 63;
    int rg = threadIdx.x >> 6;  // 0..3
    float4 acc[4];
#pragma unroll
    for (int r = 0; r < 4; r++) acc[r] = make_float4(0.f, 0.f, 0.f, 0.f);

    for (int hp = 0; hp < HH; hp += 4) {
        float4 w0 = wt4[(hp + 0) * 64 + c];
        float4 w1 = wt4[(hp + 1) * 64 + c];
        float4 w2 = wt4[(hp + 2) * 64 + c];
        float4 w3 = wt4[(hp + 3) * 64 + c];
#pragma unroll
        for (int r = 0; r < 4; r++) {
            float4 xv = *(const float4*)&x_l[rg + 4 * r][hp];
            fma4(acc[r], w0, xv.x);
            fma4(acc[r], w1, xv.y);
            fma4(acc[r], w2, xv.z);
            fma4(acc[r], w3, xv.w);
        }
    }
    float4 bias = b4[c];
#pragma unroll
    for (int r = 0; r < 4; r++) {
        acc[r].x += bias.x; acc[r].y += bias.y; acc[r].z += bias.z; acc[r].w += bias.w;
    }

    if (is_q) {
        float4* out4 = (float4*)(ws + Q_OFF + row0 * HH);
#pragma unroll
        for (int r = 0; r < 4; r++) out4[(rg + 4 * r) * 64 + c] = acc[r];
    } else {
        // stage k rows, then write K^T[h][krow] coalesced-ish (16 lanes contiguous)
#pragma unroll
        for (int r = 0; r < 4; r++) *(float4*)&st[rg + 4 * r][4 * c] = acc[r];
        __syncthreads();
        int krow0 = row0 - BS;
        int jj = threadIdx.x & 15;   // local k-row
        int hb = threadIdx.x >> 4;   // 0..15
        float* ktg = ws + KT_OFF;
#pragma unroll
        for (int hh = 0; hh < 16; hh++) {
            int h = hb * 16 + hh;
            ktg[h * BS + krow0 + jj] = st[jj][h];
        }
    }
}

// K2: fused qr-table + qk + gather + scale + softmax.
// Block = (batch b, 8-row i-tile), 256 blocks x 256 threads.
// K^T staged per 16-h tile, double-buffered: ONE barrier per tile; tile t+1
// global loads (coalesced rows of K^T) issued before compute on tile t.
__global__ __launch_bounds__(256, 1) void attn_kernel(const int* __restrict__ relations,
                                                      const float* __restrict__ ws,
                                                      float* __restrict__ out) {
    __shared__ float kt[2][16][512];   // 64 KB double buffer
    __shared__ float q_l[8][256];      // 8 KB
    __shared__ float qr_l[8][128];     // 4 KB
    __shared__ float red_m[8][2];
    __shared__ float red_s[8][2];

    int tid = threadIdx.x;
    int b = blockIdx.x >> 6;
    int i0 = (blockIdx.x & 63) * 8;

    int jl = tid & 31;
    int ig = (tid >> 5) & 3;
    int jh = tid >> 7;  // 0/1
    int jc0 = 4 * jl + 128 * (2 * jh);
    int jc1 = 4 * jl + 128 * (2 * jh + 1);

    // prefetch relations (used only in epilogue; latency hidden behind k-loop)
    const int* relb = relations + (b * SS + i0) * SS;
    int4 rv[2][2];
#pragma unroll
    for (int r = 0; r < 2; r++) {
        int i_loc = ig + 4 * r;
#pragma unroll
        for (int gg = 0; gg < 2; gg++) {
            int g = 2 * jh + gg;
            rv[r][gg] = *(const int4*)(relb + i_loc * SS + 4 * jl + 128 * g);
        }
    }

    // q_l
    const float4* q4 = (const float4*)(ws + Q_OFF + (b * SS + i0) * HH);
    float4* ql4 = (float4*)&q_l[0][0];
    ql4[tid] = q4[tid];
    ql4[256 + tid] = q4[256 + tid];

    // K^T staging: row h (len 2048), batch cols b*512..+511. Fully coalesced.
    const float4* kg = (const float4*)(ws + KT_OFF);  // [256][512 f4]
    int col4 = tid & 127;
    float4 s[8];
#pragma unroll
    for (int it = 0; it < 8; it++)
        s[it] = kg[(2 * it + jh) * 512 + b * 128 + col4];  // tile 0 rows
#pragma unroll
    for (int it = 0; it < 8; it++)
        *(float4*)&kt[0][2 * it + jh][4 * col4] = s[it];
    __syncthreads();

    float4 acc[2][2];
#pragma unroll
    for (int r = 0; r < 2; r++)
#pragma unroll
        for (int g = 0; g < 2; g++) acc[r][g] = make_float4(0.f, 0.f, 0.f, 0.f);

    for (int t = 0; t < 16; t++) {
        if (t < 15) {
#pragma unroll
            for (int it = 0; it < 8; it++)
                s[it] = kg[(16 * (t + 1) + 2 * it + jh) * 512 + b * 128 + col4];
        }
        if (t == 0) {
            // qr_l[i][r] = q[i] . rel_emb[r]  (via re_t[h][r]); overlaps tile-1 loads
            int rr = tid >> 5;   // 0..7
            int c2 = tid & 31;
            if (c2 < 25) {
                const float4* ret4 = (const float4*)(ws + RET_OFF);
                float4 a = make_float4(0.f, 0.f, 0.f, 0.f);
                for (int h4 = 0; h4 < 64; h4++) {
                    float4 qv = *(const float4*)&q_l[rr][4 * h4];
                    float4 e0 = ret4[(4 * h4 + 0) * 32 + c2];
                    float4 e1 = ret4[(4 * h4 + 1) * 32 + c2];
                    float4 e2 = ret4[(4 * h4 + 2) * 32 + c2];
                    float4 e3 = ret4[(4 * h4 + 3) * 32 + c2];
                    fma4(a, e0, qv.x);
                    fma4(a, e1, qv.y);
                    fma4(a, e2, qv.z);
                    fma4(a, e3, qv.w);
                }
                *(float4*)&qr_l[rr][4 * c2] = a;
            }
        }
        // compute on buffer t&1, h range [16t, 16t+16)
        const float(*kb)[512] = kt[t & 1];
        int h0 = 16 * t;
#pragma unroll
        for (int hh4 = 0; hh4 < 4; hh4++) {
            float4 qa = *(const float4*)&q_l[ig][h0 + 4 * hh4];
            float4 qb = *(const float4*)&q_l[ig + 4][h0 + 4 * hh4];
            const float* qap = (const float*)&qa;
            const float* qbp = (const float*)&qb;
#pragma unroll
            for (int tt = 0; tt < 4; tt++) {
                const float* krow = &kb[4 * hh4 + tt][0];
                float4 k0 = *(const float4*)(krow + jc0);
                float4 k1 = *(const float4*)(krow + jc1);
                fma4(acc[0][0], k0, qap[tt]);
                fma4(acc[0][1], k1, qap[tt]);
                fma4(acc[1][0], k0, qbp[tt]);
                fma4(acc[1][1], k1, qbp[tt]);
            }
        }
        if (t < 15) {
#pragma unroll
            for (int it = 0; it < 8; it++)
                *(float4*)&kt[(t + 1) & 1][2 * it + jh][4 * col4] = s[it];
        }
        __syncthreads();
    }

    // epilogue: logits = (qk + qr) * scale; softmax over 512 j per row
    const float scale = 0.0625f;  // 1/sqrt(256)
    float lg[2][2][4];
#pragma unroll
    for (int r = 0; r < 2; r++) {
        int i_loc = ig + 4 * r;
#pragma unroll
        for (int gg = 0; gg < 2; gg++) {
            const int* rp = (const int*)&rv[r][gg];
            const float* ap = (const float*)&acc[r][gg];
#pragma unroll
            for (int tt = 0; tt < 4; tt++)
                lg[r][gg][tt] = (ap[tt] + qr_l[i_loc][rp[tt]]) * scale;
        }
    }

    float ml[2];
#pragma unroll
    for (int r = 0; r < 2; r++) {
        float m = -1e30f;
#pragma unroll
        for (int gg = 0; gg < 2; gg++)
#pragma unroll
            for (int tt = 0; tt < 4; tt++) m = fmaxf(m, lg[r][gg][tt]);
#pragma unroll
        for (int d = 16; d >= 1; d >>= 1) m = fmaxf(m, __shfl_xor(m, d, 32));
        ml[r] = m;
    }
    if (jl == 0) {
        red_m[ig][jh] = ml[0];
        red_m[ig + 4][jh] = ml[1];
    }
    __syncthreads();
    float M[2];
    M[0] = fmaxf(red_m[ig][0], red_m[ig][1]);
    M[1] = fmaxf(red_m[ig + 4][0], red_m[ig + 4][1]);

    float sl[2] = {0.f, 0.f};
#pragma unroll
    for (int r = 0; r < 2; r++) {
#pragma unroll
        for (int gg = 0; gg < 2; gg++)
#pragma unroll
            for (int tt = 0; tt < 4; tt++) {
                float e = __expf(lg[r][gg][tt] - M[r]);
                lg[r][gg][tt] = e;
                sl[r] += e;
            }
#pragma unroll
        for (int d = 16; d >= 1; d >>= 1) sl[r] += __shfl_xor(sl[r], d, 32);
    }
    if (jl == 0) {
        red_s[ig][jh] = sl[0];
        red_s[ig + 4][jh] = sl[1];
    }
    __syncthreads();
    float inv[2];
    inv[0] = 1.f / (red_s[ig][0] + red_s[ig][1]);
    inv[1] = 1.f / (red_s[ig + 4][0] + red_s[ig + 4][1]);

    float4* outb = (float4*)(out + (b * SS + i0) * SS);
#pragma unroll
    for (int r = 0; r < 2; r++) {
        int i_loc = ig + 4 * r;
#pragma unroll
        for (int gg = 0; gg < 2; gg++) {
            int g = 2 * jh + gg;
            float4 ov;
            ov.x = lg[r][gg][0] * inv[r];
            ov.y = lg[r][gg][1] * inv[r];
            ov.z = lg[r][gg][2] * inv[r];
            ov.w = lg[r][gg][3] * inv[r];
            outb[i_loc * 128 + jl + 32 * g] = ov;
        }
    }
}

extern "C" void kernel_launch(void* const* d_in, const int* in_sizes, int n_in,
                              void* d_out, int out_size, void* d_ws, size_t ws_size,
                              hipStream_t stream) {
    const float* queries = (const float*)d_in[0];
    const float* keys = (const float*)d_in[1];
    const int* relations = (const int*)d_in[2];
    const float* Wq = (const float*)d_in[3];
    const float* bq = (const float*)d_in[4];
    const float* Wk = (const float*)d_in[5];
    const float* bk = (const float*)d_in[6];
    const float* rel_emb = (const float*)d_in[7];
    float* ws = (float*)d_ws;
    float* out = (float*)d_out;

    hipLaunchKernelGGL(prep_kernel, dim3(8, 8, 3), dim3(256), 0, stream, Wq, Wk, rel_emb, ws);
    hipLaunchKernelGGL(proj_kernel, dim3(256), dim3(256), 0, stream, queries, keys, bq, bk, ws);
    hipLaunchKernelGGL(attn_kernel, dim3(256), dim3(256), 0, stream, relations, ws, out);
}

// Round 4
// 99.823 us; speedup vs baseline: 1.5645x; 1.4158x over previous
//
#include <hip/hip_runtime.h>

typedef __attribute__((ext_vector_type(8))) short bf8;
typedef __attribute__((ext_vector_type(4))) float f4;

// ws layout (short-element offsets)
#define QBF  0         // q  bf16 [2048][256]
#define KBF  524288    // k  bf16 [2048][256]
#define WQBF 1048576   // Wq bf16 [256][256]
#define WKBF 1114112   // Wk bf16 [256][256]
#define REBF 1179648   // rel_emb bf16 [112][256], rows 99..111 zero

static __device__ __forceinline__ short bfr(float x) {
    union { float f; unsigned u; } v; v.f = x;
    return (short)((v.u + 0x7FFF + ((v.u >> 16) & 1)) >> 16);  // RNE
}
static __device__ __forceinline__ bf8 pack8(float4 a, float4 b) {
    bf8 r;
    r[0] = bfr(a.x); r[1] = bfr(a.y); r[2] = bfr(a.z); r[3] = bfr(a.w);
    r[4] = bfr(b.x); r[5] = bfr(b.y); r[6] = bfr(b.z); r[7] = bfr(b.w);
    return r;
}

// K0: cast Wq, Wk -> bf16; rel_emb -> bf16 padded to 112 rows (zeros).
// 78 blocks x 256 thr x 8 elems = 159744 elems exactly.
__global__ __launch_bounds__(256) void cast_kernel(const float* __restrict__ Wq,
                                                   const float* __restrict__ Wk,
                                                   const float* __restrict__ re,
                                                   short* __restrict__ ws) {
    int e8 = (blockIdx.x * 256 + threadIdx.x) * 8;
    float4 a = make_float4(0.f, 0.f, 0.f, 0.f), b = a;
    short* dst;
    if (e8 < 65536) {
        const float4* s = (const float4*)(Wq + e8);
        a = s[0]; b = s[1];
        dst = ws + WQBF + e8;
    } else if (e8 < 131072) {
        const float4* s = (const float4*)(Wk + (e8 - 65536));
        a = s[0]; b = s[1];
        dst = ws + WKBF + (e8 - 65536);
    } else {
        int idx = e8 - 131072;
        dst = ws + REBF + idx;
        if ((idx >> 8) < 99) {
            const float4* s = (const float4*)(re + idx);
            a = s[0]; b = s[1];
        }
    }
    *(bf8*)dst = pack8(a, b);
}

// K1: proj GEMM via MFMA. out[row][col] = sum_h x[row][h]*W[col][h] + bias[col].
// Both operands K-major -> direct-global fragment loads, no LDS.
// Block: 512 thr (8 waves), tile M=128 x N=64. Grid 128 (64 q + 64 k).
__global__ __launch_bounds__(512) void proj_kernel(const float* __restrict__ queries,
                                                   const float* __restrict__ keys,
                                                   const float* __restrict__ bq,
                                                   const float* __restrict__ bk,
                                                   short* __restrict__ ws) {
    int mat = blockIdx.x >> 6;
    int t = blockIdx.x & 63;
    int m0 = (t >> 2) * 128;
    int n0 = (t & 3) * 64;
    int w = threadIdx.x >> 6;
    int lane = threadIdx.x & 63;
    int n15 = lane & 15, quad = lane >> 4;

    const float* x = mat ? keys : queries;
    const short* wb = ws + (mat ? WKBF : WQBF);
    const float* bias = mat ? bk : bq;
    short* outp = ws + (mat ? KBF : QBF);

    // A-frags: lane holds x[m0+w*16 + n15][kk*32 + quad*8 .. +8], fp32 -> bf16 inline
    int mrow = m0 + w * 16 + n15;
    bf8 afr[8];
#pragma unroll
    for (int kk = 0; kk < 8; kk++) {
        const float4* ap = (const float4*)(x + mrow * 256 + kk * 32 + quad * 8);
        afr[kk] = pack8(ap[0], ap[1]);
    }

    f4 z = {0.f, 0.f, 0.f, 0.f};
    f4 c[4] = {z, z, z, z};
#pragma unroll
    for (int nt = 0; nt < 4; nt++) {
        int col = n0 + nt * 16 + n15;
        const short* wr = wb + col * 256 + quad * 8;
#pragma unroll
        for (int kk = 0; kk < 8; kk++) {
            bf8 bfrag = *(const bf8*)(wr + kk * 32);
            c[nt] = __builtin_amdgcn_mfma_f32_16x16x32_bf16(afr[kk], bfrag, c[nt], 0, 0, 0);
        }
    }

    // epilogue: C row = quad*4+reg, col = nt*16+n15; +bias, cvt, store bf16
    int mbase = m0 + w * 16 + quad * 4;
#pragma unroll
    for (int nt = 0; nt < 4; nt++) {
        int col = n0 + nt * 16 + n15;
        float bv = bias[col];
#pragma unroll
        for (int reg = 0; reg < 4; reg++)
            outp[(mbase + reg) * 256 + col] = bfr(c[nt][reg] + bv);
    }
}

// K2: fused qk + qr + softmax. Block = (b, 16-row i-tile) -> grid 128, 512 thr.
// Wave w handles j in [w*64, w*64+64): 4 MFMA n-tiles x 8 k-steps, frags direct
// from global (L2-hot bf16 q/k). Waves 0..6 additionally compute the qr table
// (16 i x 112 rel) via MFMA into LDS. relations prefetched at kernel start.
__global__ __launch_bounds__(512) void attn_kernel(const int* __restrict__ relations,
                                                   const short* __restrict__ ws,
                                                   float* __restrict__ out) {
    __shared__ float qr_l[16][112];
    __shared__ float red_m[16][8];
    __shared__ float red_s[16][8];

    int b = blockIdx.x >> 5;
    int i0 = (blockIdx.x & 31) * 16;
    int gi0 = b * 512 + i0;
    int w = threadIdx.x >> 6;
    int lane = threadIdx.x & 63;
    int n15 = lane & 15, quad = lane >> 4;
    int j0 = w * 64;

    // prefetch relations: rows i = i0+quad*4+reg, cols j = j0+nt*16+n15
    const int* rb = relations + (gi0 + quad * 4) * 512 + j0 + n15;
    int rv[4][4];
#pragma unroll
    for (int reg = 0; reg < 4; reg++)
#pragma unroll
        for (int nt = 0; nt < 4; nt++)
            rv[nt][reg] = rb[reg * 512 + nt * 16];

    const short* qbf = ws + QBF;
    const short* kbf = ws + KBF;
    const short* rebf = ws + REBF;

    // A-frags: q rows gi0 + n15
    int arow = gi0 + n15;
    bf8 afr[8];
#pragma unroll
    for (int kk = 0; kk < 8; kk++)
        afr[kk] = *(const bf8*)(qbf + arow * 256 + kk * 32 + quad * 8);

    f4 z = {0.f, 0.f, 0.f, 0.f};
    f4 c[4] = {z, z, z, z};
#pragma unroll
    for (int nt = 0; nt < 4; nt++) {
        int krow = b * 512 + j0 + nt * 16 + n15;
        const short* kr = kbf + krow * 256 + quad * 8;
#pragma unroll
        for (int kk = 0; kk < 8; kk++) {
            bf8 bfrag = *(const bf8*)(kr + kk * 32);
            c[nt] = __builtin_amdgcn_mfma_f32_16x16x32_bf16(afr[kk], bfrag, c[nt], 0, 0, 0);
        }
    }

    if (w < 7) {  // qr tile: rel rows w*16..w*16+15 (rebf zero-padded to 112)
        f4 cq = z;
        const short* rr = rebf + (w * 16 + n15) * 256 + quad * 8;
#pragma unroll
        for (int kk = 0; kk < 8; kk++) {
            bf8 bfrag = *(const bf8*)(rr + kk * 32);
            cq = __builtin_amdgcn_mfma_f32_16x16x32_bf16(afr[kk], bfrag, cq, 0, 0, 0);
        }
#pragma unroll
        for (int reg = 0; reg < 4; reg++)
            qr_l[quad * 4 + reg][w * 16 + n15] = cq[reg];
    }
    __syncthreads();

    const float scale = 0.0625f;  // 1/sqrt(256)
    float lg[4][4];
#pragma unroll
    for (int nt = 0; nt < 4; nt++)
#pragma unroll
        for (int reg = 0; reg < 4; reg++)
            lg[nt][reg] = (c[nt][reg] + qr_l[quad * 4 + reg][rv[nt][reg]]) * scale;

    // row max: per-lane over 4 nt, shfl over 16 lanes (n15), then cross-wave LDS
    float pm[4];
#pragma unroll
    for (int reg = 0; reg < 4; reg++) {
        float m = fmaxf(fmaxf(lg[0][reg], lg[1][reg]), fmaxf(lg[2][reg], lg[3][reg]));
#pragma unroll
        for (int d = 1; d <= 8; d <<= 1) m = fmaxf(m, __shfl_xor(m, d, 64));
        pm[reg] = m;
    }
    if (n15 == 0)
#pragma unroll
        for (int reg = 0; reg < 4; reg++) red_m[quad * 4 + reg][w] = pm[reg];
    __syncthreads();
    float M[4];
#pragma unroll
    for (int reg = 0; reg < 4; reg++) {
        f4 a0 = *(const f4*)&red_m[quad * 4 + reg][0];
        f4 a1 = *(const f4*)&red_m[quad * 4 + reg][4];
        M[reg] = fmaxf(fmaxf(fmaxf(a0[0], a0[1]), fmaxf(a0[2], a0[3])),
                       fmaxf(fmaxf(a1[0], a1[1]), fmaxf(a1[2], a1[3])));
    }

    float ps[4];
#pragma unroll
    for (int reg = 0; reg < 4; reg++) {
        float s = 0.f;
#pragma unroll
        for (int nt = 0; nt < 4; nt++) {
            float e = __expf(lg[nt][reg] - M[reg]);
            lg[nt][reg] = e;
            s += e;
        }
#pragma unroll
        for (int d = 1; d <= 8; d <<= 1) s += __shfl_xor(s, d, 64);
        ps[reg] = s;
    }
    if (n15 == 0)
#pragma unroll
        for (int reg = 0; reg < 4; reg++) red_s[quad * 4 + reg][w] = ps[reg];
    __syncthreads();
    float inv[4];
#pragma unroll
    for (int reg = 0; reg < 4; reg++) {
        f4 a0 = *(const f4*)&red_s[quad * 4 + reg][0];
        f4 a1 = *(const f4*)&red_s[quad * 4 + reg][4];
        inv[reg] = 1.f / (a0[0] + a0[1] + a0[2] + a0[3] + a1[0] + a1[1] + a1[2] + a1[3]);
    }

    float* ob = out + (gi0 + quad * 4) * 512 + j0 + n15;
#pragma unroll
    for (int reg = 0; reg < 4; reg++)
#pragma unroll
        for (int nt = 0; nt < 4; nt++)
            ob[reg * 512 + nt * 16] = lg[nt][reg] * inv[reg];
}

extern "C" void kernel_launch(void* const* d_in, const int* in_sizes, int n_in,
                              void* d_out, int out_size, void* d_ws, size_t ws_size,
                              hipStream_t stream) {
    const float* queries = (const float*)d_in[0];
    const float* keys = (const float*)d_in[1];
    const int* relations = (const int*)d_in[2];
    const float* Wq = (const float*)d_in[3];
    const float* bq = (const float*)d_in[4];
    const float* Wk = (const float*)d_in[5];
    const float* bk = (const float*)d_in[6];
    const float* rel_emb = (const float*)d_in[7];
    short* wss = (short*)d_ws;
    float* out = (float*)d_out;

    hipLaunchKernelGGL(cast_kernel, dim3(78), dim3(256), 0, stream, Wq, Wk, rel_emb, wss);
    hipLaunchKernelGGL(proj_kernel, dim3(128), dim3(512), 0, stream, queries, keys, bq, bk, wss);
    hipLaunchKernelGGL(attn_kernel, dim3(128), dim3(512), 0, stream, relations, wss, out);
}